// Round 11
// baseline (200.620 us; speedup 1.0000x reference)
//
#include <hip/hip_runtime.h>
#include <hip/hip_bf16.h>
#include <math.h>

#define NHEADS 8
#define CHVAL 32
#define SCB 1024
#define WPB 4   // waves (nodes) per block in node_kernel

// Histogram of dst -> cnt.
__global__ void hist_kernel(const int* __restrict__ dst, int* __restrict__ cnt, int E) {
    int e = blockIdx.x * blockDim.x + threadIdx.x;
    if (e < E) atomicAdd(&cnt[dst[e]], 1);
}

// Pass 1: per-block exclusive scan of cnt (in place), block totals -> btot.
__global__ void scan1_kernel(int* __restrict__ cnt, int* __restrict__ btot, int N) {
    __shared__ int sh[SCB];
    int t = threadIdx.x;
    int i = blockIdx.x * SCB + t;
    int v = (i < N) ? cnt[i] : 0;
    sh[t] = v;
    __syncthreads();
    for (int off = 1; off < SCB; off <<= 1) {
        int y = (t >= off) ? sh[t - off] : 0;
        __syncthreads();
        sh[t] += y;
        __syncthreads();
    }
    if (i < N) cnt[i] = sh[t] - v;          // exclusive within block
    if (t == SCB - 1) btot[blockIdx.x] = sh[t];
}

// Pass 2: single small block scans the (<=64) block totals, exclusive, in place.
__global__ void scan2_kernel(int* __restrict__ btot, int nb) {
    __shared__ int sh[64];
    int t = threadIdx.x;
    int v = (t < nb) ? btot[t] : 0;
    sh[t] = v;
    __syncthreads();
    for (int off = 1; off < 64; off <<= 1) {
        int y = (t >= off) ? sh[t - off] : 0;
        __syncthreads();
        sh[t] += y;
        __syncthreads();
    }
    if (t < nb) btot[t] = sh[t] - v;
}

// Pass 3: offs/cursor = local + block offset; offs[N] = E.
__global__ void scan3_kernel(const int* __restrict__ cnt, const int* __restrict__ btot,
                             int* __restrict__ offs, int* __restrict__ cursor,
                             int N, int E) {
    int i = blockIdx.x * blockDim.x + threadIdx.x;
    if (i < N) {
        int o = cnt[i] + btot[i >> 10];
        offs[i] = o;
        cursor[i] = o;
    }
    if (i == 0) offs[N] = E;
}

// Bucket edges by dst into eid[]/nid[] using cursor.
__global__ void scatter_kernel(const int* __restrict__ dst,
                               int* __restrict__ cursor,
                               int* __restrict__ eid,
                               int* __restrict__ nid,
                               int E) {
    int e = blockIdx.x * blockDim.x + threadIdx.x;
    if (e < E) {
        int n = dst[e];
        int pos = atomicAdd(&cursor[n], 1);
        eid[pos] = e;
        nid[pos] = n;
    }
}

// CSR-ordered logits: thread per (pos, head). Key reads are random 512B
// granules; q reads are SORTED by node (CSR order -> L1/L2 hits); logits
// write is fully coalesced, and node_kernel's logit reads become contiguous.
__global__ void logits_csr_kernel(const float4* __restrict__ key0,   // [E*8] float4
                                  const float4* __restrict__ key1,   // [E*24] float4
                                  const float4* __restrict__ q0,     // [N*8] float4
                                  const float4* __restrict__ q1,     // [N*24] float4
                                  const int* __restrict__ eid,       // [E]
                                  const int* __restrict__ nid,       // [E]
                                  float* __restrict__ logits,        // [E*8] CSR order
                                  int EH) {
    int tid = blockIdx.x * blockDim.x + threadIdx.x;
    if (tid >= EH) return;
    int pos = tid >> 3;
    int h = tid & 7;
    int e = eid[pos];
    int n = nid[pos];
    int kh = e * 8 + h;
    int qh = n * 8 + h;

    float4 a = key0[kh];
    float4 qa = q0[qh];
    float dot = a.x * qa.x + a.y * qa.y + a.z * qa.z + a.w * qa.w;
#pragma unroll
    for (int j = 0; j < 3; ++j) {
        float4 b  = key1[kh * 3 + j];
        float4 qb = q1[qh * 3 + j];
        dot += b.x * qb.x + b.y * qb.y + b.z * qb.z + b.w * qb.w;
    }
    logits[tid] = dot * 0.08838834764831845f;  // 1/sqrt(128)
}

// One WAVE (64 lanes) per node; WPB waves per block, fully independent
// (disjoint LDS slices, no s_barrier). Logits are CSR-ordered: lane t reads
// logits[(beg+t)*8] -> the wave's logit load is one contiguous 2KB segment.
// Values gathered via eid as before. NOTE: R6-verified body except the logit
// addressing. Do NOT hand-unroll the value loop (R8/R9 regression) and do
// NOT load offs[n] as int2 (4B align).
__global__ void __launch_bounds__(64 * WPB)
node_kernel(const float* __restrict__ logits,    // [E*8] CSR order
            const float4* __restrict__ value0,   // [E*8]  float4
            const float4* __restrict__ value1,   // [E*24] float4
            const int* __restrict__ offs,        // [N+1]
            const int* __restrict__ eid,         // [E]
            float4* __restrict__ out0,           // [N*8]  float4
            float4* __restrict__ out1,           // [N*24] float4
            int N) {
    __shared__ float w_sh[WPB][64][9];           // padded: stride 9 banks

    int wv = threadIdx.x >> 6;
    int t  = threadIdx.x & 63;
    int n  = blockIdx.x * WPB + wv;
    if (n >= N) return;

    int beg = offs[n];
    int deg = offs[n + 1] - beg;

    if (deg == 0) {
        float4 z = {0.f, 0.f, 0.f, 0.f};
        if (t < 8) out0[(size_t)n * 8 + t] = z;
        else if (t < 32) out1[(size_t)n * 24 + (t - 8)] = z;
        return;
    }

    // chunk-0 logits: lane t -> CSR slot beg+t, 8 heads (32B contiguous,
    // coalesced across the wave)
    int myeid = -1;
    float lg[8];
    if (t < deg) {
        myeid = eid[beg + t];
        const float4* lp = (const float4*)(logits + (size_t)(beg + t) * 8);
        float4 a = lp[0], b = lp[1];
        lg[0] = a.x; lg[1] = a.y; lg[2] = a.z; lg[3] = a.w;
        lg[4] = b.x; lg[5] = b.y; lg[6] = b.z; lg[7] = b.w;
    } else {
#pragma unroll
        for (int k = 0; k < 8; ++k) lg[k] = -INFINITY;
    }

    // per-head max (running over rare extra chunks)
    float mx[8];
#pragma unroll
    for (int k = 0; k < 8; ++k) mx[k] = lg[k];
    for (int base = 64; base < deg; base += 64) {       // rare: deg > 64
        if (base + t < deg) {
            const float4* lp = (const float4*)(logits + (size_t)(beg + base + t) * 8);
            float4 a = lp[0], b = lp[1];
            float tt[8] = {a.x, a.y, a.z, a.w, b.x, b.y, b.z, b.w};
#pragma unroll
            for (int k = 0; k < 8; ++k) mx[k] = fmaxf(mx[k], tt[k]);
        }
    }
#pragma unroll
    for (int k = 0; k < 8; ++k)
        for (int off = 32; off; off >>= 1)
            mx[k] = fmaxf(mx[k], __shfl_xor(mx[k], off, 64));

    // per-head sum of exp (exp(-inf - m) = 0 handles inactive lanes)
    float ex0[8], sm[8];
#pragma unroll
    for (int k = 0; k < 8; ++k) { ex0[k] = __expf(lg[k] - mx[k]); sm[k] = ex0[k]; }
    for (int base = 64; base < deg; base += 64) {       // rare
        if (base + t < deg) {
            const float4* lp = (const float4*)(logits + (size_t)(beg + base + t) * 8);
            float4 a = lp[0], b = lp[1];
            float tt[8] = {a.x, a.y, a.z, a.w, b.x, b.y, b.z, b.w};
#pragma unroll
            for (int k = 0; k < 8; ++k) sm[k] += __expf(tt[k] - mx[k]);
        }
    }
#pragma unroll
    for (int k = 0; k < 8; ++k)
        for (int off = 32; off; off >>= 1)
            sm[k] += __shfl_xor(sm[k], off, 64);
    float inv[8];
#pragma unroll
    for (int k = 0; k < 8; ++k) inv[k] = 1.0f / sm[k];

    // value accumulation: each 32-lane half owns alternate edges; lane's
    // float4 is a single-head slice (myh) of value0/value1.
    int half = t >> 5;
    int l = t & 31;
    int myh = (l < 8) ? l : ((l - 8) / 3);
    float4 acc = {0.f, 0.f, 0.f, 0.f};

    for (int base = 0; base < deg; base += 64) {
        int clen = min(64, deg - base);
        if (base == 0) {
            if (t < clen) {
#pragma unroll
                for (int k = 0; k < 8; ++k) w_sh[wv][t][k] = ex0[k] * inv[k];
            }
        } else {                                        // rare
            if (base + t < deg) {
                const float4* lp = (const float4*)(logits + (size_t)(beg + base + t) * 8);
                float4 a = lp[0], b = lp[1];
                float tt[8] = {a.x, a.y, a.z, a.w, b.x, b.y, b.z, b.w};
#pragma unroll
                for (int k = 0; k < 8; ++k)
                    w_sh[wv][t][k] = __expf(tt[k] - mx[k]) * inv[k];
            }
        }
        __builtin_amdgcn_wave_barrier();  // compiler fence: DS pipe is in-order per wave

        for (int ii = half; ii < clen; ii += 2) {
            int e = (base == 0) ? __shfl(myeid, ii, 64)
                                : eid[beg + base + ii];
            float w = w_sh[wv][ii][myh];
            float4 v = (l < 8) ? value0[(size_t)e * 8 + l]
                               : value1[(size_t)e * 24 + (l - 8)];
            acc.x += w * v.x;
            acc.y += w * v.y;
            acc.z += w * v.z;
            acc.w += w * v.w;
        }
        __builtin_amdgcn_wave_barrier();
    }

    // cross-half reduce, lanes 0-31 store
    acc.x += __shfl_xor(acc.x, 32, 64);
    acc.y += __shfl_xor(acc.y, 32, 64);
    acc.z += __shfl_xor(acc.z, 32, 64);
    acc.w += __shfl_xor(acc.w, 32, 64);
    if (t < 8)       out0[(size_t)n * 8 + l] = acc;
    else if (t < 32) out1[(size_t)n * 24 + (l - 8)] = acc;
}

extern "C" void kernel_launch(void* const* d_in, const int* in_sizes, int n_in,
                              void* d_out, int out_size, void* d_ws, size_t ws_size,
                              hipStream_t stream) {
    const float* key0   = (const float*)d_in[0];
    const float* key1   = (const float*)d_in[1];
    const float* value0 = (const float*)d_in[2];
    const float* value1 = (const float*)d_in[3];
    const float* query0 = (const float*)d_in[4];
    const float* query1 = (const float*)d_in[5];
    const int*   dst    = (const int*)d_in[6];

    int E = in_sizes[0] / CHVAL;   // 500000
    int N = in_sizes[4] / CHVAL;   // 50000
    int EH = E * NHEADS;
    int nb = (N + SCB - 1) / SCB;  // 49

    // workspace layout (4-byte elements)
    float* logits = (float*)d_ws;            // EH (CSR order)
    int*   cnt    = (int*)(logits + EH);     // N (reused as local-scan)
    int*   offs   = cnt + N;                 // N+1
    int*   cursor = offs + N + 1;            // N
    int*   eid    = cursor + N;              // E
    int*   nid    = eid + E;                 // E
    int*   btot   = nid + E;                 // 64

    float* out0 = (float*)d_out;             // N*32
    float* out1 = out0 + (size_t)N * 32;     // N*96

    hipMemsetAsync(cnt, 0, (size_t)N * sizeof(int), stream);

    int blk = 256;
    hist_kernel<<<(E + blk - 1) / blk, blk, 0, stream>>>(dst, cnt, E);

    scan1_kernel<<<nb, SCB, 0, stream>>>(cnt, btot, N);
    scan2_kernel<<<1, 64, 0, stream>>>(btot, nb);
    scan3_kernel<<<(N + blk - 1) / blk, blk, 0, stream>>>(cnt, btot, offs, cursor, N, E);

    scatter_kernel<<<(E + blk - 1) / blk, blk, 0, stream>>>(dst, cursor, eid, nid, E);

    logits_csr_kernel<<<(EH + blk - 1) / blk, blk, 0, stream>>>(
        (const float4*)key0, (const float4*)key1,
        (const float4*)query0, (const float4*)query1,
        eid, nid, logits, EH);

    int nnb = (N + WPB - 1) / WPB;
    node_kernel<<<nnb, 64 * WPB, 0, stream>>>(logits,
                                              (const float4*)value0,
                                              (const float4*)value1,
                                              offs, eid,
                                              (float4*)out0, (float4*)out1, N);
}

// Round 12
// 194.042 us; speedup vs baseline: 1.0339x; 1.0339x over previous
//
#include <hip/hip_runtime.h>
#include <hip/hip_bf16.h>
#include <math.h>

#define NHEADS 8
#define CHVAL 32
#define SCB 1024
#define WPB 4   // waves (nodes) per block in node_fused_kernel

// Histogram of dst -> cnt.
__global__ void hist_kernel(const int* __restrict__ dst, int* __restrict__ cnt, int E) {
    int e = blockIdx.x * blockDim.x + threadIdx.x;
    if (e < E) atomicAdd(&cnt[dst[e]], 1);
}

// Pass 1: per-block exclusive scan of cnt (in place), block totals -> btot.
__global__ void scan1_kernel(int* __restrict__ cnt, int* __restrict__ btot, int N) {
    __shared__ int sh[SCB];
    int t = threadIdx.x;
    int i = blockIdx.x * SCB + t;
    int v = (i < N) ? cnt[i] : 0;
    sh[t] = v;
    __syncthreads();
    for (int off = 1; off < SCB; off <<= 1) {
        int y = (t >= off) ? sh[t - off] : 0;
        __syncthreads();
        sh[t] += y;
        __syncthreads();
    }
    if (i < N) cnt[i] = sh[t] - v;          // exclusive within block
    if (t == SCB - 1) btot[blockIdx.x] = sh[t];
}

// Pass 2: single small block scans the (<=64) block totals, exclusive, in place.
__global__ void scan2_kernel(int* __restrict__ btot, int nb) {
    __shared__ int sh[64];
    int t = threadIdx.x;
    int v = (t < nb) ? btot[t] : 0;
    sh[t] = v;
    __syncthreads();
    for (int off = 1; off < 64; off <<= 1) {
        int y = (t >= off) ? sh[t - off] : 0;
        __syncthreads();
        sh[t] += y;
        __syncthreads();
    }
    if (t < nb) btot[t] = sh[t] - v;
}

// Pass 3: offs/cursor = local + block offset; offs[N] = E.
__global__ void scan3_kernel(const int* __restrict__ cnt, const int* __restrict__ btot,
                             int* __restrict__ offs, int* __restrict__ cursor,
                             int N, int E) {
    int i = blockIdx.x * blockDim.x + threadIdx.x;
    if (i < N) {
        int o = cnt[i] + btot[i >> 10];
        offs[i] = o;
        cursor[i] = o;
    }
    if (i == 0) offs[N] = E;
}

// Bucket edges by dst into eid[] using cursor.
__global__ void scatter_kernel(const int* __restrict__ dst,
                               int* __restrict__ cursor,
                               int* __restrict__ eid,
                               int E) {
    int e = blockIdx.x * blockDim.x + threadIdx.x;
    if (e < E) {
        int pos = atomicAdd(&cursor[dst[e]], 1);
        eid[pos] = e;
    }
}

// Fully fused, one WAVE per node, ONLINE softmax (single uniform chunk loop —
// no code duplication, unlike R7). Lane layout for the logit phase: t=(s,h),
// 8 lanes cooperate per edge (512B-contiguous key segments). Running per-head
// max m and denom s live in ONE scalar register each (after shfl_xor 8/16/32
// reduces every lane of head h holds head-h's value). Per chunk: unnormalized
// weights + eids + per-head rescale -> LDS; value phase (R6-verified layout)
// rescales acc and accumulates. Final acc *= 1/s. WPB independent waves per
// block, no s_barrier. Do NOT hand-unroll the value loop (R8/R9 regression).
__global__ void __launch_bounds__(64 * WPB)
node_fused_kernel(const float4* __restrict__ key0,     // [E*8]  float4
                  const float4* __restrict__ key1,     // [E*24] float4
                  const float4* __restrict__ q0,       // [N*8]  float4
                  const float4* __restrict__ q1,       // [N*24] float4
                  const float4* __restrict__ value0,   // [E*8]  float4
                  const float4* __restrict__ value1,   // [E*24] float4
                  const int* __restrict__ offs,        // [N+1]
                  const int* __restrict__ eid,         // [E]
                  float4* __restrict__ out0,           // [N*8]  float4
                  float4* __restrict__ out1,           // [N*24] float4
                  int N) {
    __shared__ float w_sh[WPB][64][9];                 // padded stride
    __shared__ int   e_sh[WPB][64];
    __shared__ float scale_sh[WPB][8];

    int wv = threadIdx.x >> 6;
    int t  = threadIdx.x & 63;
    int n  = blockIdx.x * WPB + wv;
    if (n >= N) return;

    int beg = offs[n];
    int deg = offs[n + 1] - beg;

    if (deg == 0) {
        float4 z = {0.f, 0.f, 0.f, 0.f};
        if (t < 8) out0[(size_t)n * 8 + t] = z;
        else if (t < 32) out1[(size_t)n * 24 + (t - 8)] = z;
        return;
    }

    const float SCALE = 0.08838834764831845f;          // 1/sqrt(128)
    int s = t >> 3;                                    // edge sub-slot
    int h = t & 7;                                     // head

    // this node's query slice for head h (64B, register-resident)
    float4 qa  = q0[(size_t)n * 8 + h];
    float4 qb0 = q1[(size_t)n * 24 + 3 * h + 0];
    float4 qb1 = q1[(size_t)n * 24 + 3 * h + 1];
    float4 qb2 = q1[(size_t)n * 24 + 3 * h + 2];

    // value-phase lane layout (R6-verified)
    int half = t >> 5;
    int l = t & 31;
    int myh = (l < 8) ? l : ((l - 8) / 3);

    float m_run = -INFINITY;
    float s_run = 0.0f;
    float4 acc = {0.f, 0.f, 0.f, 0.f};

    for (int base = 0; base < deg; base += 64) {
        int clen = min(64, deg - base);

        // --- logit phase: lane computes head h of slots base + r*8 + s ---
        float lgreg[8];
#pragma unroll
        for (int r = 0; r < 8; ++r) {
            int slot = base + r * 8 + s;
            float lg = -INFINITY;
            if (slot < deg) {
                int e = eid[beg + slot];
                if (h == 0) e_sh[wv][r * 8 + s] = e;
                float4 ka  = key0[(size_t)e * 8 + h];
                float4 kb0 = key1[(size_t)e * 24 + 3 * h + 0];
                float4 kb1 = key1[(size_t)e * 24 + 3 * h + 1];
                float4 kb2 = key1[(size_t)e * 24 + 3 * h + 2];
                float d = ka.x * qa.x + ka.y * qa.y + ka.z * qa.z + ka.w * qa.w
                        + kb0.x * qb0.x + kb0.y * qb0.y + kb0.z * qb0.z + kb0.w * qb0.w
                        + kb1.x * qb1.x + kb1.y * qb1.y + kb1.z * qb1.z + kb1.w * qb1.w
                        + kb2.x * qb2.x + kb2.y * qb2.y + kb2.z * qb2.z + kb2.w * qb2.w;
                lg = d * SCALE;
            }
            lgreg[r] = lg;
        }

        // per-head chunk max (in-lane over r, then across s-groups)
        float cm = lgreg[0];
#pragma unroll
        for (int r = 1; r < 8; ++r) cm = fmaxf(cm, lgreg[r]);
        cm = fmaxf(cm, __shfl_xor(cm, 8, 64));
        cm = fmaxf(cm, __shfl_xor(cm, 16, 64));
        cm = fmaxf(cm, __shfl_xor(cm, 32, 64));

        float new_m = fmaxf(m_run, cm);
        float rescale = __expf(m_run - new_m);         // 0 on first chunk (m=-inf)

        float chsum = 0.0f;
#pragma unroll
        for (int r = 0; r < 8; ++r) chsum += __expf(lgreg[r] - new_m);  // -inf -> 0
        chsum += __shfl_xor(chsum, 8, 64);
        chsum += __shfl_xor(chsum, 16, 64);
        chsum += __shfl_xor(chsum, 32, 64);

        s_run = s_run * rescale + chsum;
        m_run = new_m;

        // unnormalized weights into LDS (invalid slots write 0 — harmless)
#pragma unroll
        for (int r = 0; r < 8; ++r)
            w_sh[wv][r * 8 + s][h] = __expf(lgreg[r] - new_m);
        if (t < 8) scale_sh[wv][t] = rescale;          // lane t has h==t
        __builtin_amdgcn_wave_barrier();  // compiler fence; DS in-order per wave

        // --- value phase: rescale acc, accumulate this chunk ---
        float rs = scale_sh[wv][myh];
        acc.x *= rs; acc.y *= rs; acc.z *= rs; acc.w *= rs;

        for (int ii = half; ii < clen; ii += 2) {
            int e = e_sh[wv][ii];
            float w = w_sh[wv][ii][myh];
            float4 v = (l < 8) ? value0[(size_t)e * 8 + l]
                               : value1[(size_t)e * 24 + (l - 8)];
            acc.x += w * v.x;
            acc.y += w * v.y;
            acc.z += w * v.z;
            acc.w += w * v.w;
        }
        __builtin_amdgcn_wave_barrier();               // before next chunk overwrites LDS
    }

    // final normalization: 1/s broadcast per head
    if (t < 8) scale_sh[wv][t] = 1.0f / s_run;
    __builtin_amdgcn_wave_barrier();
    float inv = scale_sh[wv][myh];
    acc.x *= inv; acc.y *= inv; acc.z *= inv; acc.w *= inv;

    // cross-half reduce, lanes 0-31 store
    acc.x += __shfl_xor(acc.x, 32, 64);
    acc.y += __shfl_xor(acc.y, 32, 64);
    acc.z += __shfl_xor(acc.z, 32, 64);
    acc.w += __shfl_xor(acc.w, 32, 64);
    if (t < 8)       out0[(size_t)n * 8 + l] = acc;
    else if (t < 32) out1[(size_t)n * 24 + (l - 8)] = acc;
}

extern "C" void kernel_launch(void* const* d_in, const int* in_sizes, int n_in,
                              void* d_out, int out_size, void* d_ws, size_t ws_size,
                              hipStream_t stream) {
    const float* key0   = (const float*)d_in[0];
    const float* key1   = (const float*)d_in[1];
    const float* value0 = (const float*)d_in[2];
    const float* value1 = (const float*)d_in[3];
    const float* query0 = (const float*)d_in[4];
    const float* query1 = (const float*)d_in[5];
    const int*   dst    = (const int*)d_in[6];

    int E = in_sizes[0] / CHVAL;   // 500000
    int N = in_sizes[4] / CHVAL;   // 50000
    int nb = (N + SCB - 1) / SCB;  // 49

    // workspace layout (4-byte elements)
    int* cnt    = (int*)d_ws;                // N (reused as local-scan)
    int* offs   = cnt + N;                   // N+1
    int* cursor = offs + N + 1;              // N
    int* eid    = cursor + N;                // E
    int* btot   = eid + E;                   // 64

    float* out0 = (float*)d_out;             // N*32
    float* out1 = out0 + (size_t)N * 32;     // N*96

    hipMemsetAsync(cnt, 0, (size_t)N * sizeof(int), stream);

    int blk = 256;
    hist_kernel<<<(E + blk - 1) / blk, blk, 0, stream>>>(dst, cnt, E);

    scan1_kernel<<<nb, SCB, 0, stream>>>(cnt, btot, N);
    scan2_kernel<<<1, 64, 0, stream>>>(btot, nb);
    scan3_kernel<<<(N + blk - 1) / blk, blk, 0, stream>>>(cnt, btot, offs, cursor, N, E);

    scatter_kernel<<<(E + blk - 1) / blk, blk, 0, stream>>>(dst, cursor, eid, E);

    int nnb = (N + WPB - 1) / WPB;
    node_fused_kernel<<<nnb, 64 * WPB, 0, stream>>>(
        (const float4*)key0, (const float4*)key1,
        (const float4*)query0, (const float4*)query1,
        (const float4*)value0, (const float4*)value1,
        offs, eid,
        (float4*)out0, (float4*)out1, N);
}